// Round 3
// baseline (464.621 us; speedup 1.0000x reference)
//
#include <hip/hip_runtime.h>

#define HIDDEN 512
#define SEQN 4096
#define BM 128
#define BK 64

typedef __attribute__((ext_vector_type(8))) short short8;
typedef __attribute__((ext_vector_type(4))) float f32x4;

__device__ __forceinline__ short f2bf(float f) {
  unsigned u = __float_as_uint(f);
  u = u + 0x7FFFu + ((u >> 16) & 1u);   // round-to-nearest-even
  return (short)(u >> 16);
}

// packed f32x2 -> bf16x2 (RNE), lo = a, hi = b
__device__ __forceinline__ unsigned cvtpk(float a, float b) {
  unsigned r;
  asm("v_cvt_pk_bf16_f32 %0, %1, %2" : "=v"(r) : "v"(a), "v"(b));
  return r;
}

// Kernel 0: convert We = attn_w[:, 512:] (f32, row-major [k][1024]) -> wbf [k][512] bf16
__global__ void k_convW(const float* __restrict__ attn_w, short* __restrict__ wbf) {
  int i = blockIdx.x * 256 + threadIdx.x;      // 65536 threads
  int f = i * 4;                                // element quad
  int k = f >> 9;
  int h = f & 511;
  const float4 v = *reinterpret_cast<const float4*>(attn_w + k * 1024 + 512 + h);
  uint2 o = { cvtpk(v.x, v.y), cvtpk(v.z, v.w) };
  *reinterpret_cast<uint2*>(wbf + f) = o;
}

// Kernel 1: hp[b][k] = attn_b[k] + sum_h hidden[b][h] * attn_w[k][h]   (f32 exact)
__global__ void k_hproj(const float* __restrict__ hidden, const float* __restrict__ attn_w,
                        const float* __restrict__ attn_b, float* __restrict__ hp) {
  int b = blockIdx.y;
  int k = blockIdx.x * 128 + threadIdx.x;
  __shared__ float hsh[HIDDEN];
  *reinterpret_cast<float4*>(hsh + threadIdx.x * 4) =
      *reinterpret_cast<const float4*>(hidden + b * HIDDEN + threadIdx.x * 4);
  __syncthreads();
  const float* wr = attn_w + k * 1024;
  float4 s4 = {0.f, 0.f, 0.f, 0.f};
  #pragma unroll 8
  for (int h = 0; h < HIDDEN; h += 4) {
    float4 wv = *reinterpret_cast<const float4*>(wr + h);
    s4.x += wv.x * hsh[h];
    s4.y += wv.y * hsh[h + 1];
    s4.z += wv.z * hsh[h + 2];
    s4.w += wv.w * hsh[h + 3];
  }
  hp[b * HIDDEN + k] = attn_b[k] + ((s4.x + s4.y) + (s4.z + s4.w));
}

// Kernel 2: fused  e_proj GEMM (bf16 MFMA) + tanh + v-dot  -> scores[b][s]
// grid 1024 blocks (32 s-tiles x 32 b), 512 threads (8 waves), wave tile 128x64.
// Double-buffered LDS A tile, ONE barrier per K-step.
__global__ __launch_bounds__(512, 2) void k_main(
    const float* __restrict__ enc, const short* __restrict__ wbf,
    const float* __restrict__ hp, const float* __restrict__ vw,
    float* __restrict__ scores) {
  __shared__ __align__(16) short A_ls[2][BM * BK];   // 32 KB, XOR-swizzled
  __shared__ float part[8][BM];                      // 4 KB

  const int tid = threadIdx.x;
  const int w = tid >> 6;          // wave 0..7 -> owns cols [w*64, w*64+64)
  const int l = tid & 63;
  const int lq = l >> 4;           // quarter
  const int lr = l & 15;

  const int bid = blockIdx.x;
  const int b = bid >> 5;
  const int s0 = (bid & 31) * BM;
  const float* encB = enc + ((size_t)b * SEQN + s0) * HIDDEN;

  // staging assignment: thread handles rows r0 and r0+64, col-group cg (8 f32 each)
  const int r0 = tid >> 3;         // 0..63
  const int cg = tid & 7;
  const int wa0 = r0 * 64 + ((cg * 8) ^ ((r0 & 7) << 3));
  const int wa1 = (r0 + 64) * 64 + ((cg * 8) ^ ((r0 & 7) << 3));

  const short* wBase = wbf + (w * 64 + lr) * HIDDEN + lq * 8;

  f32x4 acc[8][4];
  #pragma unroll
  for (int mi = 0; mi < 8; ++mi)
    #pragma unroll
    for (int ni = 0; ni < 4; ++ni)
      acc[mi][ni] = (f32x4){0.f, 0.f, 0.f, 0.f};

  // prologue: load + stage tile 0
  float4 ga0, ga1, gb0, gb1;
  {
    const float* p0 = encB + r0 * HIDDEN + cg * 8;
    const float* p1 = p0 + 64 * HIDDEN;
    ga0 = *reinterpret_cast<const float4*>(p0);
    ga1 = *reinterpret_cast<const float4*>(p0 + 4);
    gb0 = *reinterpret_cast<const float4*>(p1);
    gb1 = *reinterpret_cast<const float4*>(p1 + 4);
  }
  {
    uint4 u0 = { cvtpk(ga0.x, ga0.y), cvtpk(ga0.z, ga0.w), cvtpk(ga1.x, ga1.y), cvtpk(ga1.z, ga1.w) };
    uint4 u1 = { cvtpk(gb0.x, gb0.y), cvtpk(gb0.z, gb0.w), cvtpk(gb1.x, gb1.y), cvtpk(gb1.z, gb1.w) };
    *reinterpret_cast<uint4*>(&A_ls[0][wa0]) = u0;
    *reinterpret_cast<uint4*>(&A_ls[0][wa1]) = u1;
  }
  __syncthreads();

  #pragma unroll
  for (int st = 0; st < 8; ++st) {
    const int cur = st & 1;
    // issue next A-tile global loads first (latency hidden under MFMA phase)
    if (st < 7) {
      const float* p0 = encB + r0 * HIDDEN + (st + 1) * BK + cg * 8;
      const float* p1 = p0 + 64 * HIDDEN;
      ga0 = *reinterpret_cast<const float4*>(p0);
      ga1 = *reinterpret_cast<const float4*>(p0 + 4);
      gb0 = *reinterpret_cast<const float4*>(p1);
      gb1 = *reinterpret_cast<const float4*>(p1 + 4);
    }
    // W fragments for this K-step (L2-resident; kk1 covered by kk0's MFMAs)
    short8 wf0[4], wf1[4];
    #pragma unroll
    for (int ni = 0; ni < 4; ++ni)
      wf0[ni] = *reinterpret_cast<const short8*>(wBase + ni * (16 * HIDDEN) + st * BK);
    #pragma unroll
    for (int ni = 0; ni < 4; ++ni)
      wf1[ni] = *reinterpret_cast<const short8*>(wBase + ni * (16 * HIDDEN) + st * BK + 32);

    // kk = 0
    {
      short8 af[8];
      #pragma unroll
      for (int mi = 0; mi < 8; ++mi)
        af[mi] = *reinterpret_cast<const short8*>(
            &A_ls[cur][(mi * 16 + lr) * 64 + ((lq * 8) ^ ((lr & 7) << 3))]);
      #pragma unroll
      for (int mi = 0; mi < 8; ++mi)
        #pragma unroll
        for (int ni = 0; ni < 4; ++ni)
          acc[mi][ni] = __builtin_amdgcn_mfma_f32_16x16x32_bf16(af[mi], wf0[ni], acc[mi][ni], 0, 0, 0);
    }
    // kk = 1
    {
      short8 af[8];
      #pragma unroll
      for (int mi = 0; mi < 8; ++mi)
        af[mi] = *reinterpret_cast<const short8*>(
            &A_ls[cur][(mi * 16 + lr) * 64 + ((32 + lq * 8) ^ ((lr & 7) << 3))]);
      #pragma unroll
      for (int mi = 0; mi < 8; ++mi)
        #pragma unroll
        for (int ni = 0; ni < 4; ++ni)
          acc[mi][ni] = __builtin_amdgcn_mfma_f32_16x16x32_bf16(af[mi], wf1[ni], acc[mi][ni], 0, 0, 0);
    }
    // stage next tile into the other buffer (reads of it finished 2 barriers ago)
    if (st < 7) {
      uint4 u0 = { cvtpk(ga0.x, ga0.y), cvtpk(ga0.z, ga0.w), cvtpk(ga1.x, ga1.y), cvtpk(ga1.z, ga1.w) };
      uint4 u1 = { cvtpk(gb0.x, gb0.y), cvtpk(gb0.z, gb0.w), cvtpk(gb1.x, gb1.y), cvtpk(gb1.z, gb1.w) };
      *reinterpret_cast<uint4*>(&A_ls[cur ^ 1][wa0]) = u0;
      *reinterpret_cast<uint4*>(&A_ls[cur ^ 1][wa1]) = u1;
    }
    __syncthreads();
  }

  // Epilogue: e = tanh(acc + hp[b][col]) * v[col]; reduce over cols
  float hpv[4], vv[4];
  {
    const float* hpb = hp + b * HIDDEN;
    const int colb = w * 64 + lr;
    #pragma unroll
    for (int ni = 0; ni < 4; ++ni) {
      hpv[ni] = hpb[colb + ni * 16];
      vv[ni]  = vw[colb + ni * 16];
    }
  }
  float rp[8][4];
  #pragma unroll
  for (int mi = 0; mi < 8; ++mi)
    #pragma unroll
    for (int r = 0; r < 4; ++r) {
      float s = 0.f;
      #pragma unroll
      for (int ni = 0; ni < 4; ++ni) {
        float x = acc[mi][ni][r] + hpv[ni];
        float e = __expf(2.0f * x);
        float th = 1.0f - 2.0f / (e + 1.0f);   // tanh(x)
        s += th * vv[ni];
      }
      rp[mi][r] = s;
    }
  #pragma unroll
  for (int mk = 1; mk <= 8; mk <<= 1)
    #pragma unroll
    for (int mi = 0; mi < 8; ++mi)
      #pragma unroll
      for (int r = 0; r < 4; ++r)
        rp[mi][r] += __shfl_xor(rp[mi][r], mk, 64);
  if (lr == 0) {
    #pragma unroll
    for (int mi = 0; mi < 8; ++mi)
      #pragma unroll
      for (int r = 0; r < 4; ++r)
        part[w][mi * 16 + lq * 4 + r] = rp[mi][r];
  }
  __syncthreads();
  if (tid < BM) {
    float s = 0.f;
    #pragma unroll
    for (int ww = 0; ww < 8; ++ww) s += part[ww][tid];
    scores[b * SEQN + s0 + tid] = s;
  }
}

// Kernel 3: row softmax over s=4096, one block per b
__global__ void k_softmax(const float* __restrict__ scores, float* __restrict__ out) {
  const int b = blockIdx.x;
  const int t = threadIdx.x;   // 256 threads, 16 values each
  const float* row = scores + b * SEQN;
  float4 x[4];
  #pragma unroll
  for (int i = 0; i < 4; ++i)
    x[i] = *reinterpret_cast<const float4*>(row + (i * 256 + t) * 4);
  float m = -1e30f;
  #pragma unroll
  for (int i = 0; i < 4; ++i)
    m = fmaxf(m, fmaxf(fmaxf(x[i].x, x[i].y), fmaxf(x[i].z, x[i].w)));
  #pragma unroll
  for (int mk = 1; mk < 64; mk <<= 1) m = fmaxf(m, __shfl_xor(m, mk, 64));
  __shared__ float redmax[4], redsum[4];
  if ((t & 63) == 0) redmax[t >> 6] = m;
  __syncthreads();
  m = fmaxf(fmaxf(redmax[0], redmax[1]), fmaxf(redmax[2], redmax[3]));
  float sum = 0.f;
  #pragma unroll
  for (int i = 0; i < 4; ++i) {
    x[i].x = __expf(x[i].x - m); sum += x[i].x;
    x[i].y = __expf(x[i].y - m); sum += x[i].y;
    x[i].z = __expf(x[i].z - m); sum += x[i].z;
    x[i].w = __expf(x[i].w - m); sum += x[i].w;
  }
  #pragma unroll
  for (int mk = 1; mk < 64; mk <<= 1) sum += __shfl_xor(sum, mk, 64);
  if ((t & 63) == 0) redsum[t >> 6] = sum;
  __syncthreads();
  sum = redsum[0] + redsum[1] + redsum[2] + redsum[3];
  float inv = 1.0f / sum;
  #pragma unroll
  for (int i = 0; i < 4; ++i) {
    float4 o = { x[i].x * inv, x[i].y * inv, x[i].z * inv, x[i].w * inv };
    *reinterpret_cast<float4*>(out + b * SEQN + (i * 256 + t) * 4) = o;
  }
}

extern "C" void kernel_launch(void* const* d_in, const int* in_sizes, int n_in,
                              void* d_out, int out_size, void* d_ws, size_t ws_size,
                              hipStream_t stream) {
  const float* hidden = (const float*)d_in[0];
  const float* enc    = (const float*)d_in[1];
  const float* attn_w = (const float*)d_in[2];
  const float* attn_b = (const float*)d_in[3];
  const float* vw     = (const float*)d_in[4];
  float* out = (float*)d_out;

  short* wbf    = (short*)d_ws;                                   // 512 KB
  float* hp     = (float*)((char*)d_ws + 512 * 1024);             // 64 KB
  float* scores = (float*)((char*)d_ws + 512 * 1024 + 64 * 1024); // 512 KB

  k_convW<<<256, 256, 0, stream>>>(attn_w, wbf);
  k_hproj<<<dim3(4, 32), 128, 0, stream>>>(hidden, attn_w, attn_b, hp);
  k_main<<<1024, 512, 0, stream>>>(enc, wbf, hp, vw, scores);
  k_softmax<<<32, 256, 0, stream>>>(scores, out);
}

// Round 4
// 456.432 us; speedup vs baseline: 1.0179x; 1.0179x over previous
//
#include <hip/hip_runtime.h>

#define HIDDEN 512
#define SEQN 4096
#define BM 128
#define BK 64

typedef __attribute__((ext_vector_type(8))) short short8;
typedef __attribute__((ext_vector_type(4))) float f32x4;

// packed f32x2 -> bf16x2 (RNE), lo = a, hi = b
__device__ __forceinline__ unsigned cvtpk(float a, float b) {
  unsigned r;
  asm("v_cvt_pk_bf16_f32 %0, %1, %2" : "=v"(r) : "v"(a), "v"(b));
  return r;
}

// Kernel 0: convert We = attn_w[:, 512:] (f32, row-major [k][1024]) -> wbf [k][512] bf16
__global__ void k_convW(const float* __restrict__ attn_w, short* __restrict__ wbf) {
  int i = blockIdx.x * 256 + threadIdx.x;      // 65536 threads
  int f = i * 4;                                // element quad
  int k = f >> 9;
  int h = f & 511;
  const float4 v = *reinterpret_cast<const float4*>(attn_w + k * 1024 + 512 + h);
  uint2 o = { cvtpk(v.x, v.y), cvtpk(v.z, v.w) };
  *reinterpret_cast<uint2*>(wbf + f) = o;
}

// Kernel 1: hp[b][k] = attn_b[k] + sum_h hidden[b][h] * attn_w[k][h]   (f32 exact)
__global__ void k_hproj(const float* __restrict__ hidden, const float* __restrict__ attn_w,
                        const float* __restrict__ attn_b, float* __restrict__ hp) {
  int b = blockIdx.y;
  int k = blockIdx.x * 128 + threadIdx.x;
  __shared__ float hsh[HIDDEN];
  *reinterpret_cast<float4*>(hsh + threadIdx.x * 4) =
      *reinterpret_cast<const float4*>(hidden + b * HIDDEN + threadIdx.x * 4);
  __syncthreads();
  const float* wr = attn_w + k * 1024;
  float4 s4 = {0.f, 0.f, 0.f, 0.f};
  #pragma unroll 8
  for (int h = 0; h < HIDDEN; h += 4) {
    float4 wv = *reinterpret_cast<const float4*>(wr + h);
    s4.x += wv.x * hsh[h];
    s4.y += wv.y * hsh[h + 1];
    s4.z += wv.z * hsh[h + 2];
    s4.w += wv.w * hsh[h + 3];
  }
  hp[b * HIDDEN + k] = attn_b[k] + ((s4.x + s4.y) + (s4.z + s4.w));
}

// Kernel 2: fused  e_proj GEMM (bf16 MFMA) + tanh + v-dot  -> scores[b][s]
// grid 1024 blocks (32 s-tiles x 32 b), 512 threads (8 waves), wave tile 128x64.
// Double-buffered LDS A tile, ONE barrier per K-step. ROLLED st loop
// (unroll 1: full unroll made the compiler hoist cross-step W loads -> 8MB spills, R3).
__global__ __launch_bounds__(512, 2) void k_main(
    const float* __restrict__ enc, const short* __restrict__ wbf,
    const float* __restrict__ hp, const float* __restrict__ vw,
    float* __restrict__ scores) {
  __shared__ __align__(16) short A_ls[2][BM * BK];   // 32 KB, XOR-swizzled
  __shared__ float part[8][BM];                      // 4 KB

  const int tid = threadIdx.x;
  const int w = tid >> 6;          // wave 0..7 -> owns cols [w*64, w*64+64)
  const int l = tid & 63;
  const int lq = l >> 4;           // quarter
  const int lr = l & 15;

  const int bid = blockIdx.x;
  const int b = bid >> 5;
  const int s0 = (bid & 31) * BM;
  const float* encB = enc + ((size_t)b * SEQN + s0) * HIDDEN;

  // staging assignment: thread handles rows r0 and r0+64, col-group cg (8 f32 each)
  const int r0 = tid >> 3;         // 0..63
  const int cg = tid & 7;
  const int wa0 = r0 * 64 + ((cg * 8) ^ ((r0 & 7) << 3));
  const int wa1 = (r0 + 64) * 64 + ((cg * 8) ^ ((r0 & 7) << 3));

  const short* wBase = wbf + (w * 64 + lr) * HIDDEN + lq * 8;

  f32x4 acc[8][4];
  #pragma unroll
  for (int mi = 0; mi < 8; ++mi)
    #pragma unroll
    for (int ni = 0; ni < 4; ++ni)
      acc[mi][ni] = (f32x4){0.f, 0.f, 0.f, 0.f};

  // prologue: load + stage tile 0
  float4 ga0, ga1, gb0, gb1;
  {
    const float* p0 = encB + r0 * HIDDEN + cg * 8;
    const float* p1 = p0 + 64 * HIDDEN;
    ga0 = *reinterpret_cast<const float4*>(p0);
    ga1 = *reinterpret_cast<const float4*>(p0 + 4);
    gb0 = *reinterpret_cast<const float4*>(p1);
    gb1 = *reinterpret_cast<const float4*>(p1 + 4);
  }
  {
    uint4 u0 = { cvtpk(ga0.x, ga0.y), cvtpk(ga0.z, ga0.w), cvtpk(ga1.x, ga1.y), cvtpk(ga1.z, ga1.w) };
    uint4 u1 = { cvtpk(gb0.x, gb0.y), cvtpk(gb0.z, gb0.w), cvtpk(gb1.x, gb1.y), cvtpk(gb1.z, gb1.w) };
    *reinterpret_cast<uint4*>(&A_ls[0][wa0]) = u0;
    *reinterpret_cast<uint4*>(&A_ls[0][wa1]) = u1;
  }
  __syncthreads();

  #pragma unroll 1
  for (int st = 0; st < 8; ++st) {
    const int cur = st & 1;
    // issue next A-tile global loads first (latency hidden under MFMA phase)
    if (st < 7) {
      const float* p0 = encB + r0 * HIDDEN + (st + 1) * BK + cg * 8;
      const float* p1 = p0 + 64 * HIDDEN;
      ga0 = *reinterpret_cast<const float4*>(p0);
      ga1 = *reinterpret_cast<const float4*>(p0 + 4);
      gb0 = *reinterpret_cast<const float4*>(p1);
      gb1 = *reinterpret_cast<const float4*>(p1 + 4);
    }
    // W fragments for this K-step (L2-resident; kk1 covered by kk0's MFMAs)
    short8 wf0[4], wf1[4];
    #pragma unroll
    for (int ni = 0; ni < 4; ++ni)
      wf0[ni] = *reinterpret_cast<const short8*>(wBase + ni * (16 * HIDDEN) + st * BK);
    #pragma unroll
    for (int ni = 0; ni < 4; ++ni)
      wf1[ni] = *reinterpret_cast<const short8*>(wBase + ni * (16 * HIDDEN) + st * BK + 32);

    // kk = 0
    {
      short8 af[8];
      #pragma unroll
      for (int mi = 0; mi < 8; ++mi)
        af[mi] = *reinterpret_cast<const short8*>(
            &A_ls[cur][(mi * 16 + lr) * 64 + ((lq * 8) ^ ((lr & 7) << 3))]);
      #pragma unroll
      for (int mi = 0; mi < 8; ++mi)
        #pragma unroll
        for (int ni = 0; ni < 4; ++ni)
          acc[mi][ni] = __builtin_amdgcn_mfma_f32_16x16x32_bf16(af[mi], wf0[ni], acc[mi][ni], 0, 0, 0);
    }
    // kk = 1
    {
      short8 af[8];
      #pragma unroll
      for (int mi = 0; mi < 8; ++mi)
        af[mi] = *reinterpret_cast<const short8*>(
            &A_ls[cur][(mi * 16 + lr) * 64 + ((32 + lq * 8) ^ ((lr & 7) << 3))]);
      #pragma unroll
      for (int mi = 0; mi < 8; ++mi)
        #pragma unroll
        for (int ni = 0; ni < 4; ++ni)
          acc[mi][ni] = __builtin_amdgcn_mfma_f32_16x16x32_bf16(af[mi], wf1[ni], acc[mi][ni], 0, 0, 0);
    }
    // stage next tile into the other buffer (reads of it finished 2 barriers ago)
    if (st < 7) {
      uint4 u0 = { cvtpk(ga0.x, ga0.y), cvtpk(ga0.z, ga0.w), cvtpk(ga1.x, ga1.y), cvtpk(ga1.z, ga1.w) };
      uint4 u1 = { cvtpk(gb0.x, gb0.y), cvtpk(gb0.z, gb0.w), cvtpk(gb1.x, gb1.y), cvtpk(gb1.z, gb1.w) };
      *reinterpret_cast<uint4*>(&A_ls[cur ^ 1][wa0]) = u0;
      *reinterpret_cast<uint4*>(&A_ls[cur ^ 1][wa1]) = u1;
    }
    __syncthreads();
  }

  // Epilogue: e = tanh(acc + hp[b][col]) * v[col]; reduce over cols
  float hpv[4], vv[4];
  {
    const float* hpb = hp + b * HIDDEN;
    const int colb = w * 64 + lr;
    #pragma unroll
    for (int ni = 0; ni < 4; ++ni) {
      hpv[ni] = hpb[colb + ni * 16];
      vv[ni]  = vw[colb + ni * 16];
    }
  }
  float rp[8][4];
  #pragma unroll
  for (int mi = 0; mi < 8; ++mi)
    #pragma unroll
    for (int r = 0; r < 4; ++r) {
      float s = 0.f;
      #pragma unroll
      for (int ni = 0; ni < 4; ++ni) {
        float x = acc[mi][ni][r] + hpv[ni];
        float e = __expf(2.0f * x);
        float th = 1.0f - 2.0f / (e + 1.0f);   // tanh(x)
        s += th * vv[ni];
      }
      rp[mi][r] = s;
    }
  #pragma unroll
  for (int mk = 1; mk <= 8; mk <<= 1)
    #pragma unroll
    for (int mi = 0; mi < 8; ++mi)
      #pragma unroll
      for (int r = 0; r < 4; ++r)
        rp[mi][r] += __shfl_xor(rp[mi][r], mk, 64);
  if (lr == 0) {
    #pragma unroll
    for (int mi = 0; mi < 8; ++mi)
      #pragma unroll
      for (int r = 0; r < 4; ++r)
        part[w][mi * 16 + lq * 4 + r] = rp[mi][r];
  }
  __syncthreads();
  if (tid < BM) {
    float s = 0.f;
    #pragma unroll
    for (int ww = 0; ww < 8; ++ww) s += part[ww][tid];
    scores[b * SEQN + s0 + tid] = s;
  }
}

// Kernel 3: row softmax over s=4096, one block per b
__global__ void k_softmax(const float* __restrict__ scores, float* __restrict__ out) {
  const int b = blockIdx.x;
  const int t = threadIdx.x;   // 256 threads, 16 values each
  const float* row = scores + b * SEQN;
  float4 x[4];
  #pragma unroll
  for (int i = 0; i < 4; ++i)
    x[i] = *reinterpret_cast<const float4*>(row + (i * 256 + t) * 4);
  float m = -1e30f;
  #pragma unroll
  for (int i = 0; i < 4; ++i)
    m = fmaxf(m, fmaxf(fmaxf(x[i].x, x[i].y), fmaxf(x[i].z, x[i].w)));
  #pragma unroll
  for (int mk = 1; mk < 64; mk <<= 1) m = fmaxf(m, __shfl_xor(m, mk, 64));
  __shared__ float redmax[4], redsum[4];
  if ((t & 63) == 0) redmax[t >> 6] = m;
  __syncthreads();
  m = fmaxf(fmaxf(redmax[0], redmax[1]), fmaxf(redmax[2], redmax[3]));
  float sum = 0.f;
  #pragma unroll
  for (int i = 0; i < 4; ++i) {
    x[i].x = __expf(x[i].x - m); sum += x[i].x;
    x[i].y = __expf(x[i].y - m); sum += x[i].y;
    x[i].z = __expf(x[i].z - m); sum += x[i].z;
    x[i].w = __expf(x[i].w - m); sum += x[i].w;
  }
  #pragma unroll
  for (int mk = 1; mk < 64; mk <<= 1) sum += __shfl_xor(sum, mk, 64);
  if ((t & 63) == 0) redsum[t >> 6] = sum;
  __syncthreads();
  sum = redsum[0] + redsum[1] + redsum[2] + redsum[3];
  float inv = 1.0f / sum;
  #pragma unroll
  for (int i = 0; i < 4; ++i) {
    float4 o = { x[i].x * inv, x[i].y * inv, x[i].z * inv, x[i].w * inv };
    *reinterpret_cast<float4*>(out + b * SEQN + (i * 256 + t) * 4) = o;
  }
}

extern "C" void kernel_launch(void* const* d_in, const int* in_sizes, int n_in,
                              void* d_out, int out_size, void* d_ws, size_t ws_size,
                              hipStream_t stream) {
  const float* hidden = (const float*)d_in[0];
  const float* enc    = (const float*)d_in[1];
  const float* attn_w = (const float*)d_in[2];
  const float* attn_b = (const float*)d_in[3];
  const float* vw     = (const float*)d_in[4];
  float* out = (float*)d_out;

  short* wbf    = (short*)d_ws;                                   // 512 KB
  float* hp     = (float*)((char*)d_ws + 512 * 1024);             // 64 KB
  float* scores = (float*)((char*)d_ws + 512 * 1024 + 64 * 1024); // 512 KB

  k_convW<<<256, 256, 0, stream>>>(attn_w, wbf);
  k_hproj<<<dim3(4, 32), 128, 0, stream>>>(hidden, attn_w, attn_b, hp);
  k_main<<<1024, 512, 0, stream>>>(enc, wbf, hp, vw, scores);
  k_softmax<<<32, 256, 0, stream>>>(scores, out);
}